// Round 10
// baseline (799.061 us; speedup 1.0000x reference)
//
#include <hip/hip_runtime.h>
#include <hip/hip_bf16.h>

#define B_SZ 8192
#define D_SZ 4096   // K
#define H_SZ 2048
#define N4H  8192   // 4*H = N (gate-interleaved n' space)
#define NT   (D_SZ / 64)   // 64 K-tiles of BK=64

typedef __attribute__((ext_vector_type(8))) __bf16 bf16x8;
typedef __attribute__((ext_vector_type(4))) float f32x4;

#define GPTR(p) ((__attribute__((address_space(1))) void*)(p))
#define LPTR(p) ((__attribute__((address_space(3))) void*)(p))

// ---------------------------------------------------------------------------
// 1) prep: [blocks 0..2047]    combine = bf16(input + hidden)
//    [blocks 2048..34815]      WT[n'][k] = bf16(W_g[k][h]),
//                              n' = (h>>4)*64 + g*16 + (h&15)   (gate-interleave)
// ---------------------------------------------------------------------------
__global__ void prep_k(const float* __restrict__ x, const float* __restrict__ h,
                       __hip_bfloat16* __restrict__ comb,
                       const float* __restrict__ Wf, const float* __restrict__ Wc,
                       const float* __restrict__ Wi, const float* __restrict__ Wo,
                       __hip_bfloat16* __restrict__ WT) {
    __shared__ float t[32][33];
    if (blockIdx.x < 2048) {
        const size_t n4 = (size_t)B_SZ * D_SZ / 4;
        const size_t stride = (size_t)2048 * 256;
        for (size_t i = (size_t)blockIdx.x * 256 + threadIdx.x; i < n4; i += stride) {
            f32x4 a = __builtin_nontemporal_load((const f32x4*)x + i);
            f32x4 b = __builtin_nontemporal_load((const f32x4*)h + i);
            short4 r;
            r.x = __builtin_bit_cast(short, __float2bfloat16(a.x + b.x));
            r.y = __builtin_bit_cast(short, __float2bfloat16(a.y + b.y));
            r.z = __builtin_bit_cast(short, __float2bfloat16(a.z + b.z));
            r.w = __builtin_bit_cast(short, __float2bfloat16(a.w + b.w));
            ((short4*)comb)[i] = r;
        }
    } else {
        const int b = blockIdx.x - 2048;      // 0..32767
        const int k0 = (b & 127) * 32;        // K block
        const int n0 = (b >> 7) * 32;         // old-layout n block (g*2048 + h)
        const float* W = (n0 < H_SZ) ? Wf : (n0 < 2 * H_SZ) ? Wc
                       : (n0 < 3 * H_SZ) ? Wi : Wo;
        const int g = n0 >> 11;
        const int nc = n0 & (H_SZ - 1);
        const int tx = threadIdx.x & 31, ty = threadIdx.x >> 5;
#pragma unroll
        for (int j = 0; j < 4; ++j)
            t[ty + j * 8][tx] = __builtin_nontemporal_load(
                W + (size_t)(k0 + ty + j * 8) * H_SZ + nc + tx);
        __syncthreads();
#pragma unroll
        for (int j = 0; j < 4; ++j) {
            const int h2 = nc + ty + j * 8;                       // h index
            const int np = ((h2 >> 4) << 6) + (g << 4) + (h2 & 15);
            WT[(size_t)np * D_SZ + k0 + tx] = __float2bfloat16(t[tx][ty + j * 8]);
        }
    }
}

// ---------------------------------------------------------------------------
// 2) GEMM + fused LSTM epilogue (v7: B-in-registers, A double-buffered LDS,
//    ONE barrier per K-tile).
//    Tile 256(M)x128(N), BK=64, 4 waves (2Mx2N), wave-tile 128x64.
//    LDS 64KB/block = A dbuf: buf p = [region0 16K][region1 16K] @ p*32768.
//    B fragments are loaded DIRECTLY global->reg (64B-coalesced: 16 rows x
//    64B per load pattern), one tile ahead into the alternate register set
//    (bA/bB swap by tile parity; no LDS, no swizzle, window = full tile).
//    Per tile: LDA r0; STAGE A(t+1)->other buf (8 gload_lds); [mem clobber]
//    load b(t+1) (8 dwordx4); MFMA q00,q01; LDA r1; MFMA q10,q11; vmcnt(8)
//    (= the 8 B loads outstanding, all A stages drained, cross-wave visible
//    after the barrier); s_barrier.
//    Buffer safety: tile t reads buf(t%2), stages buf((t+1)%2). Stages of
//    tile t+1 (into buf(t%2)) are issued only after the tile-t barrier, which
//    all waves reach after their tile-t LDAs completed (auto-lgkm before the
//    consuming MFMAs). 2 blocks/CU (128KB LDS) slip freely -> pipe overlap.
// ---------------------------------------------------------------------------

#define BAR()                                    \
    do {                                         \
        asm volatile("" ::: "memory");           \
        __builtin_amdgcn_s_barrier();            \
        asm volatile("" ::: "memory");           \
    } while (0)

// stage BOTH A regions of K-tile kt into LDS buffer at byte offset BUF
#define STAGE_A8(kt, BUF)                                                              \
    do {                                                                               \
        _Pragma("unroll") for (int h_ = 0; h_ < 2; ++h_)                               \
        _Pragma("unroll") for (int c_ = 0; c_ < 4; ++c_) {                             \
            __builtin_amdgcn_global_load_lds(                                          \
                GPTR(pA + (size_t)((c_ >> 1) * 128 + h_ * 64 + (c_ & 1) * 32) * D_SZ   \
                         + (size_t)(kt) * 64),                                         \
                LPTR(smem + (BUF) + h_ * 16384 + c_ * 4096 + wave * 1024), 16, 0, 0);  \
        }                                                                              \
    } while (0)

// read A fragment for region RB (byte offset incl. buffer)
#define LDA(dst, RB)                                                                   \
    do {                                                                               \
        _Pragma("unroll") for (int mi = 0; mi < 4; ++mi) {                             \
            const int row_ = wr * 64 + mi * 16 + fr;                                   \
            dst[mi][0] = *(const bf16x8*)(smem + (RB) + row_ * 128 + sw0);             \
            dst[mi][1] = *(const bf16x8*)(smem + (RB) + row_ * 128 + sw1);             \
        }                                                                              \
    } while (0)

// direct global->reg B fragments for quadrant qn of K-tile kt
#define LDB_G(dst, qn, kt)                                                             \
    do {                                                                               \
        _Pragma("unroll") for (int nf = 0; nf < 2; ++nf)                               \
        _Pragma("unroll") for (int ks = 0; ks < 2; ++ks)                               \
            dst[nf][ks] = *(const bf16x8*)(pBg                                         \
                + (size_t)((qn) * 32 + nf * 16) * D_SZ + (size_t)(kt) * 64 + ks * 32); \
    } while (0)

#define MFMA_Q(qm, qn, areg, breg)                                                     \
    do {                                                                               \
        _Pragma("unroll") for (int mi = 0; mi < 4; ++mi)                               \
        _Pragma("unroll") for (int nf = 0; nf < 2; ++nf)                               \
        _Pragma("unroll") for (int ks = 0; ks < 2; ++ks)                               \
            acc[(qm) * 4 + mi][(qn) * 2 + nf] =                                        \
                __builtin_amdgcn_mfma_f32_16x16x32_bf16(                               \
                    areg[mi][ks], breg[nf][ks],                                        \
                    acc[(qm) * 4 + mi][(qn) * 2 + nf], 0, 0, 0);                       \
    } while (0)

// One K-tile: compute tile t from buf CUR with regs bc; stage A(KTN) into
// OTH; load b(KTN) into bn. One barrier. KTN may be 64 (dummy prefetch —
// overruns comb into the WT region / past WT within workspace: valid memory).
#define TILE2(KTN, CUR, OTH, bc0, bc1, bn0, bn1)                                       \
    {                                                                                  \
        LDA(a, (CUR));                                                                 \
        STAGE_A8((KTN), (OTH));                                                        \
        asm volatile("" ::: "memory");  /* pin: B loads stay after stages */           \
        LDB_G(bn0, 0, (KTN));                                                          \
        LDB_G(bn1, 1, (KTN));                                                          \
        __builtin_amdgcn_s_setprio(1);                                                 \
        MFMA_Q(0, 0, a, bc0);                                                          \
        MFMA_Q(0, 1, a, bc1);                                                          \
        __builtin_amdgcn_s_setprio(0);                                                 \
        LDA(a, (CUR) + 16384);                                                         \
        __builtin_amdgcn_s_setprio(1);                                                 \
        MFMA_Q(1, 0, a, bc0);                                                          \
        MFMA_Q(1, 1, a, bc1);                                                          \
        __builtin_amdgcn_s_setprio(0);                                                 \
        asm volatile("s_waitcnt vmcnt(8)" ::: "memory"); /* A stages landed */         \
        BAR();                                                                         \
    }

__device__ __forceinline__ float fsig(float x) { return 1.f / (1.f + __expf(-x)); }
__device__ __forceinline__ float ftanh(float x) {
    x = fminf(fmaxf(x, -15.f), 15.f);
    float e = __expf(2.f * x);
    return (e - 1.f) / (e + 1.f);
}

__global__ __launch_bounds__(256, 2) void gemm4_k(
    const __hip_bfloat16* __restrict__ A,   // comb [8192][4096]
    const __hip_bfloat16* __restrict__ BT,  // WT   [8192][4096] (gate-interleaved rows)
    const float* __restrict__ cell,         // [8192][2048]
    const float* __restrict__ bfb, const float* __restrict__ bcb,
    const float* __restrict__ bib, const float* __restrict__ bob,
    float* __restrict__ out)                // [out | hid | cst], each [8192][2048]
{
    extern __shared__ char smem[];

    const int tid  = threadIdx.x;
    const int wave = tid >> 6;
    const int lane = tid & 63;
    const int wr = wave >> 1;   // 0..1  (M halves of 128)
    const int wc = wave & 1;    // 0..1  (N halves of 64)
    const int fr = lane & 15;
    const int hi = lane >> 4;   // 0..3
    const int sw0 = ((hi + 0) ^ (fr & 7)) << 4;
    const int sw1 = ((hi + 4) ^ (fr & 7)) << 4;

    // XCD-aware swizzle (bijective: 2048 % 8 == 0); n fastest so the ~64
    // co-resident blocks of an XCD share one 2MB A-panel (L2-resident).
    const int wg = (blockIdx.x & 7) * 256 + (blockIdx.x >> 3);
    const int ntile = wg & 63;
    const int m0 = (wg >> 6) * 256;
    const int n0 = ntile * 128;

    // A staging source (pre-swizzled global column; linear LDS dest)
    const int r0   = tid >> 3;                           // 0..31
    const int col0 = ((tid & 7) ^ (r0 & 7)) << 3;
    const __hip_bfloat16* pA = A + (size_t)(m0 + r0) * D_SZ + col0;
    // B direct-load base: row n0 + wc*64 + fr, k slice hi*8 (no swizzle)
    const __hip_bfloat16* pBg = BT + (size_t)(n0 + wc * 64 + fr) * D_SZ + hi * 8;

    f32x4 acc[8][4] = {};
    bf16x8 a[4][2], bA0[2][2], bA1[2][2], bB0[2][2], bB1[2][2];

    // prologue: stage A(0) into buf0, drain, barrier; load b(0) direct.
    STAGE_A8(0, 0);
    asm volatile("s_waitcnt vmcnt(0)" ::: "memory");
    BAR();
    LDB_G(bA0, 0, 0);
    LDB_G(bA1, 1, 0);

#pragma unroll 1
    for (int t = 0; t < NT; t += 2) {
        TILE2(t + 1, 0,     32768, bA0, bA1, bB0, bB1);   // tile t   (buf0)
        TILE2(t + 2, 32768, 0,     bB0, bB1, bA0, bA1);   // tile t+1 (buf1)
    }

    // ---- fused LSTM epilogue (state scoped here; K-loop live set small)
    {
        const int crow = hi * 4;
        const int ccol = fr;
        const int hh = (ntile * 2 + wc) * 16 + ccol;
        const float bf_ = bfb[hh], bc_ = bcb[hh], bi_ = bib[hh], bo_ = bob[hh];
        const size_t BH = (size_t)B_SZ * H_SZ;
        float* hidp = out + BH;
        float* cstp = out + 2 * BH;
#pragma unroll
        for (int ai = 0; ai < 8; ++ai) {
#pragma unroll
            for (int j = 0; j < 4; ++j) {
                const size_t r = (size_t)(m0 + wr * 128 + ai * 16 + crow + j);
                const size_t idx = r * H_SZ + hh;
                const float gf = acc[ai][0][j] + bf_;
                const float gc = acc[ai][1][j] + bc_;
                const float gi = acc[ai][2][j] + bi_;
                const float go = acc[ai][3][j] + bo_;
                const float ft = fsig(gf);
                const float ct = ftanh(gc);
                const float it_ = fsig(fsig(gi));   // double sigmoid, faithful
                const float ot = fsig(go);
                const float cv = __builtin_nontemporal_load(cell + idx);
                const float cs = cv * ft + ct * it_;
                __builtin_nontemporal_store(ot, out + idx);
                __builtin_nontemporal_store(cs, cstp + idx);
                __builtin_nontemporal_store(ot * ftanh(cs), hidp + idx);
            }
        }
    }

    // drain dummy prefetch (kt=64) before endpgm — next block reuses LDS
    asm volatile("s_waitcnt vmcnt(0)" ::: "memory");
}

// ---------------------------------------------------------------------------
extern "C" void kernel_launch(void* const* d_in, const int* in_sizes, int n_in,
                              void* d_out, int out_size, void* d_ws, size_t ws_size,
                              hipStream_t stream) {
    const float* input  = (const float*)d_in[0];
    const float* hidden = (const float*)d_in[1];
    const float* cell   = (const float*)d_in[2];
    const float* Wf     = (const float*)d_in[3];
    const float* bfb    = (const float*)d_in[4];
    const float* Wc     = (const float*)d_in[5];
    const float* bcb    = (const float*)d_in[6];
    const float* Wi     = (const float*)d_in[7];
    const float* bib    = (const float*)d_in[8];
    const float* Wo     = (const float*)d_in[9];
    const float* bob    = (const float*)d_in[10];
    float* out = (float*)d_out;

    char* ws = (char*)d_ws;
    __hip_bfloat16* comb = (__hip_bfloat16*)ws;                              // 64 MiB
    __hip_bfloat16* WT   = (__hip_bfloat16*)(ws + (size_t)B_SZ * D_SZ * 2);  // 64 MiB

    hipFuncSetAttribute(reinterpret_cast<const void*>(gemm4_k),
                        hipFuncAttributeMaxDynamicSharedMemorySize, 65536);

    prep_k<<<2048 + 32768, 256, 0, stream>>>(input, hidden, comb, Wf, Wc, Wi, Wo, WT);
    gemm4_k<<<2048, 256, 65536, stream>>>(comb, WT, cell, bfb, bcb, bib, bob, out);
}

// Round 11
// 593.376 us; speedup vs baseline: 1.3466x; 1.3466x over previous
//
#include <hip/hip_runtime.h>
#include <hip/hip_bf16.h>

#define B_SZ 8192
#define D_SZ 4096   // K
#define H_SZ 2048
#define N4H  8192   // 4*H = N (gate-interleaved n' space)
#define NT   (D_SZ / 64)   // 64 K-tiles of BK=64

typedef __attribute__((ext_vector_type(8))) __bf16 bf16x8;
typedef __attribute__((ext_vector_type(4))) float f32x4;

#define GPTR(p) ((__attribute__((address_space(1))) void*)(p))
#define LPTR(p) ((__attribute__((address_space(3))) void*)(p))

// ---------------------------------------------------------------------------
// 1) prep: [blocks 0..2047]    combine = bf16(input + hidden)
//    [blocks 2048..34815]      WT[n'][k] = bf16(W_g[k][h]),
//                              n' = (h>>4)*64 + g*16 + (h&15)   (gate-interleave)
// ---------------------------------------------------------------------------
__global__ void prep_k(const float* __restrict__ x, const float* __restrict__ h,
                       __hip_bfloat16* __restrict__ comb,
                       const float* __restrict__ Wf, const float* __restrict__ Wc,
                       const float* __restrict__ Wi, const float* __restrict__ Wo,
                       __hip_bfloat16* __restrict__ WT) {
    __shared__ float t[32][33];
    if (blockIdx.x < 2048) {
        const size_t n4 = (size_t)B_SZ * D_SZ / 4;
        const size_t stride = (size_t)2048 * 256;
        for (size_t i = (size_t)blockIdx.x * 256 + threadIdx.x; i < n4; i += stride) {
            f32x4 a = __builtin_nontemporal_load((const f32x4*)x + i);
            f32x4 b = __builtin_nontemporal_load((const f32x4*)h + i);
            short4 r;
            r.x = __builtin_bit_cast(short, __float2bfloat16(a.x + b.x));
            r.y = __builtin_bit_cast(short, __float2bfloat16(a.y + b.y));
            r.z = __builtin_bit_cast(short, __float2bfloat16(a.z + b.z));
            r.w = __builtin_bit_cast(short, __float2bfloat16(a.w + b.w));
            ((short4*)comb)[i] = r;
        }
    } else {
        const int b = blockIdx.x - 2048;      // 0..32767
        const int k0 = (b & 127) * 32;        // K block
        const int n0 = (b >> 7) * 32;         // old-layout n block (g*2048 + h)
        const float* W = (n0 < H_SZ) ? Wf : (n0 < 2 * H_SZ) ? Wc
                       : (n0 < 3 * H_SZ) ? Wi : Wo;
        const int g = n0 >> 11;
        const int nc = n0 & (H_SZ - 1);
        const int tx = threadIdx.x & 31, ty = threadIdx.x >> 5;
#pragma unroll
        for (int j = 0; j < 4; ++j)
            t[ty + j * 8][tx] = __builtin_nontemporal_load(
                W + (size_t)(k0 + ty + j * 8) * H_SZ + nc + tx);
        __syncthreads();
#pragma unroll
        for (int j = 0; j < 4; ++j) {
            const int h2 = nc + ty + j * 8;                       // h index
            const int np = ((h2 >> 4) << 6) + (g << 4) + (h2 & 15);
            WT[(size_t)np * D_SZ + k0 + tx] = __float2bfloat16(t[tx][ty + j * 8]);
        }
    }
}

// ---------------------------------------------------------------------------
// 2) GEMM + fused LSTM epilogue (v8 = r9 structure + stage-first phases +
//    redundant ph3 vmcnt removed).
//    Tile 256(M)x128(N), BK=64, 4 waves (2Mx2N), wave-tile 128x64.
//    LDS 64KB/block: A0@0, A1@16K (single-buffered, recycled per phase),
//    B dbuf @32K/48K. 2 blocks/CU slip freely -> LDS pipe of one block
//    overlaps MFMA pipe of the other.
//    Safety invariants (r9-proven):
//    - every ds_read's data is consumed by an MFMA in the SAME phase before
//      that phase's barrier => all waves' reads of a region completed before
//      any wave's next-phase stage writes it.
//    - vmcnt audit (loads; STAGE_B=2, STAGE_A=4):
//      end-ph1: outstanding {A0(t)4,B1(t)2,A1(t)4,B0(t+1)2}=12 -> vmcnt(6)
//               drains A0(t),B1(t)   [ph2 reads B1(t)]
//      end-ph2: {A1(t)4,B0(t+1)2,A0(t+1)4}=10 -> vmcnt(6) drains A1(t)
//               [ph3 reads A1(t)]
//      end-ph3: no vmcnt (ph4 reads no new LDS; later needs covered below)
//      end-ph4: {B0(t+1)2,A0(t+1)4,B1(t+1)2,A1(t+1)4}=12 -> vmcnt(6) drains
//               B0(t+1),A0(t+1)      [ph1(t+1) reads both]
//    - stages issued at phase TOP: same FIFO contents at each vmcnt point,
//      but DMA starts ~50-100cy earlier per phase.
// ---------------------------------------------------------------------------

#define LDS_A0 0
#define LDS_A1 16384
#define LDS_BB0 32768
#define LDS_BB1 49152

#define BAR()                                    \
    do {                                         \
        asm volatile("" ::: "memory");           \
        __builtin_amdgcn_s_barrier();            \
        asm volatile("" ::: "memory");           \
    } while (0)

// A quadrant h of K-tile kt -> region LDS_A0/A1 (4 calls x 32 rows x 128B)
#define STAGE_A(h, kt)                                                                 \
    do {                                                                               \
        _Pragma("unroll") for (int c_ = 0; c_ < 4; ++c_) {                             \
            __builtin_amdgcn_global_load_lds(                                          \
                GPTR(pA + (size_t)((c_ >> 1) * 128 + (h) * 64 + (c_ & 1) * 32) * D_SZ  \
                         + (size_t)(kt) * 64),                                         \
                LPTR(smem + (h) * 16384 + c_ * 4096 + wave * 1024), 16, 0, 0);         \
        }                                                                              \
    } while (0)

// B quadrant qn of K-tile kt -> buffer bb (2 calls x 32 rows x 128B)
#define STAGE_B(qn, kt, bb)                                                            \
    do {                                                                               \
        _Pragma("unroll") for (int c_ = 0; c_ < 2; ++c_) {                             \
            __builtin_amdgcn_global_load_lds(                                          \
                GPTR(pB + (size_t)((qn) * 32 + c_ * 64) * D_SZ + (size_t)(kt) * 64),   \
                LPTR(smem + (bb) + (qn) * 8192 + c_ * 4096 + wave * 1024), 16, 0, 0);  \
        }                                                                              \
    } while (0)

#define LDA(dst, RB)                                                                   \
    do {                                                                               \
        _Pragma("unroll") for (int mi = 0; mi < 4; ++mi) {                             \
            const int row_ = wr * 64 + mi * 16 + fr;                                   \
            dst[mi][0] = *(const bf16x8*)(smem + (RB) + row_ * 128 + sw0);             \
            dst[mi][1] = *(const bf16x8*)(smem + (RB) + row_ * 128 + sw1);             \
        }                                                                              \
    } while (0)

#define LDB(dst, BB, qn)                                                               \
    do {                                                                               \
        _Pragma("unroll") for (int nf = 0; nf < 2; ++nf) {                             \
            const int row_ = (qn) * 64 + wc * 32 + nf * 16 + fr;                       \
            dst[nf][0] = *(const bf16x8*)(smem + (BB) + row_ * 128 + sw0);             \
            dst[nf][1] = *(const bf16x8*)(smem + (BB) + row_ * 128 + sw1);             \
        }                                                                              \
    } while (0)

#define MFMA_Q(qm, qn, areg, breg)                                                     \
    do {                                                                               \
        _Pragma("unroll") for (int mi = 0; mi < 4; ++mi)                               \
        _Pragma("unroll") for (int nf = 0; nf < 2; ++nf)                               \
        _Pragma("unroll") for (int ks = 0; ks < 2; ++ks)                               \
            acc[(qm) * 4 + mi][(qn) * 2 + nf] =                                        \
                __builtin_amdgcn_mfma_f32_16x16x32_bf16(                               \
                    areg[mi][ks], breg[nf][ks],                                        \
                    acc[(qm) * 4 + mi][(qn) * 2 + nf], 0, 0, 0);                       \
    } while (0)

// One K-tile: 4 phases, 1 barrier each; stages issued at phase top.
#define TILE(KT, CURB, OTHB)                                                           \
    {                                                                                  \
        const int kt_ = (KT) & 63;                                                     \
        /* ph1: stage B0(t+1)->other; reads A0(t),B0(t); q(0,0) */                     \
        STAGE_B(0, kt_, OTHB);                                                         \
        LDA(a, LDS_A0);                                                                \
        LDB(b0, CURB, 0);                                                              \
        __builtin_amdgcn_s_setprio(1);                                                 \
        MFMA_Q(0, 0, a, b0);                                                           \
        __builtin_amdgcn_s_setprio(0);                                                 \
        asm volatile("s_waitcnt vmcnt(6)" ::: "memory");                               \
        BAR();                                                                         \
        /* ph2: stage A0(t+1) (A0 reads done @ph1); reads B1(t); q(0,1) */             \
        STAGE_A(0, kt_);                                                               \
        LDB(b1, CURB, 1);                                                              \
        __builtin_amdgcn_s_setprio(1);                                                 \
        MFMA_Q(0, 1, a, b1);                                                           \
        __builtin_amdgcn_s_setprio(0);                                                 \
        asm volatile("s_waitcnt vmcnt(6)" ::: "memory");                               \
        BAR();                                                                         \
        /* ph3: stage B1(t+1)->other; reads A1(t); q(1,0); no vmcnt needed */          \
        STAGE_B(1, kt_, OTHB);                                                         \
        LDA(a, LDS_A1);                                                                \
        __builtin_amdgcn_s_setprio(1);                                                 \
        MFMA_Q(1, 0, a, b0);                                                           \
        __builtin_amdgcn_s_setprio(0);                                                 \
        BAR();                                                                         \
        /* ph4: stage A1(t+1) (A1 reads done @ph3); q(1,1) */                          \
        STAGE_A(1, kt_);                                                               \
        __builtin_amdgcn_s_setprio(1);                                                 \
        MFMA_Q(1, 1, a, b1);                                                           \
        __builtin_amdgcn_s_setprio(0);                                                 \
        asm volatile("s_waitcnt vmcnt(6)" ::: "memory");                               \
        BAR();                                                                         \
    }

__device__ __forceinline__ float fsig(float x) { return 1.f / (1.f + __expf(-x)); }
__device__ __forceinline__ float ftanh(float x) {
    x = fminf(fmaxf(x, -15.f), 15.f);
    float e = __expf(2.f * x);
    return (e - 1.f) / (e + 1.f);
}

__global__ __launch_bounds__(256, 2) void gemm4_k(
    const __hip_bfloat16* __restrict__ A,   // comb [8192][4096]
    const __hip_bfloat16* __restrict__ BT,  // WT   [8192][4096] (gate-interleaved rows)
    const float* __restrict__ cell,         // [8192][2048]
    const float* __restrict__ bfb, const float* __restrict__ bcb,
    const float* __restrict__ bib, const float* __restrict__ bob,
    float* __restrict__ out)                // [out | hid | cst], each [8192][2048]
{
    extern __shared__ char smem[];

    const int tid  = threadIdx.x;
    const int wave = tid >> 6;
    const int lane = tid & 63;
    const int wr = wave >> 1;   // 0..1  (M halves of 128)
    const int wc = wave & 1;    // 0..1  (N halves of 64)
    const int fr = lane & 15;
    const int sw0 = (((lane >> 4) + 0) ^ (fr & 7)) << 4;
    const int sw1 = (((lane >> 4) + 4) ^ (fr & 7)) << 4;

    // XCD-aware swizzle (bijective: 2048 % 8 == 0). n fastest -> the ~64
    // co-resident blocks of an XCD share one 2MB A-panel (L2-resident).
    const int wg = (blockIdx.x & 7) * 256 + (blockIdx.x >> 3);
    const int ntile = wg & 63;
    const int m0 = (wg >> 6) * 256;
    const int n0 = ntile * 128;

    // per-thread staging sources (pre-swizzled global column; 32-row calls)
    const int r0   = tid >> 3;                           // 0..31
    const int col0 = ((tid & 7) ^ (r0 & 7)) << 3;
    const __hip_bfloat16* pA = A  + (size_t)(m0 + r0) * D_SZ + col0;
    const __hip_bfloat16* pB = BT + (size_t)(n0 + r0) * D_SZ + col0;

    f32x4 acc[8][4] = {};
    bf16x8 a[4][2], b0[2][2], b1[2][2];

    // prologue: stage tile0 in steady-state order (B0,A0,B1,A1); vmcnt(6)
    // drains B0+A0 (needed ph1), leaves B1+A1 in flight = steady invariant.
    STAGE_B(0, 0, LDS_BB0);
    STAGE_A(0, 0);
    STAGE_B(1, 0, LDS_BB0);
    STAGE_A(1, 0);
    asm volatile("s_waitcnt vmcnt(6)" ::: "memory");
    BAR();

#pragma unroll 1
    for (int t = 0; t < NT; t += 2) {
        TILE(t + 1, LDS_BB0, LDS_BB1);   // even tile t: B(t) in buf0
        TILE(t + 2, LDS_BB1, LDS_BB0);   // odd tile t+1: B in buf1 (t=63: kt wraps to 0, dummy)
    }

    // ---- fused LSTM epilogue (state scoped here; K-loop live set small)
    {
        const int crow = (lane >> 4) * 4;
        const int ccol = lane & 15;
        const int hh = (ntile * 2 + wc) * 16 + ccol;
        const float bf_ = bfb[hh], bc_ = bcb[hh], bi_ = bib[hh], bo_ = bob[hh];
        const size_t BH = (size_t)B_SZ * H_SZ;
        float* hidp = out + BH;
        float* cstp = out + 2 * BH;
#pragma unroll
        for (int ai = 0; ai < 8; ++ai) {
#pragma unroll
            for (int j = 0; j < 4; ++j) {
                const size_t r = (size_t)(m0 + wr * 128 + ai * 16 + crow + j);
                const size_t idx = r * H_SZ + hh;
                const float gf = acc[ai][0][j] + bf_;
                const float gc = acc[ai][1][j] + bc_;
                const float gi = acc[ai][2][j] + bi_;
                const float go = acc[ai][3][j] + bo_;
                const float ft = fsig(gf);
                const float ct = ftanh(gc);
                const float it_ = fsig(fsig(gi));   // double sigmoid, faithful
                const float ot = fsig(go);
                const float cv = __builtin_nontemporal_load(cell + idx);
                const float cs = cv * ft + ct * it_;
                __builtin_nontemporal_store(ot, out + idx);
                __builtin_nontemporal_store(cs, cstp + idx);
                __builtin_nontemporal_store(ot * ftanh(cs), hidp + idx);
            }
        }
    }

    // drain pending LDS-DMA (tile-63's dummy stages) before endpgm:
    // the next block on this CU reuses the LDS.
    asm volatile("s_waitcnt vmcnt(0)" ::: "memory");
}

// ---------------------------------------------------------------------------
extern "C" void kernel_launch(void* const* d_in, const int* in_sizes, int n_in,
                              void* d_out, int out_size, void* d_ws, size_t ws_size,
                              hipStream_t stream) {
    const float* input  = (const float*)d_in[0];
    const float* hidden = (const float*)d_in[1];
    const float* cell   = (const float*)d_in[2];
    const float* Wf     = (const float*)d_in[3];
    const float* bfb    = (const float*)d_in[4];
    const float* Wc     = (const float*)d_in[5];
    const float* bcb    = (const float*)d_in[6];
    const float* Wi     = (const float*)d_in[7];
    const float* bib    = (const float*)d_in[8];
    const float* Wo     = (const float*)d_in[9];
    const float* bob    = (const float*)d_in[10];
    float* out = (float*)d_out;

    char* ws = (char*)d_ws;
    __hip_bfloat16* comb = (__hip_bfloat16*)ws;                              // 64 MiB
    __hip_bfloat16* WT   = (__hip_bfloat16*)(ws + (size_t)B_SZ * D_SZ * 2);  // 64 MiB

    hipFuncSetAttribute(reinterpret_cast<const void*>(gemm4_k),
                        hipFuncAttributeMaxDynamicSharedMemorySize, 65536);

    prep_k<<<2048 + 32768, 256, 0, stream>>>(input, hidden, comb, Wf, Wc, Wi, Wo, WT);
    gemm4_k<<<2048, 256, 65536, stream>>>(comb, WT, cell, bfb, bcb, bib, bob, out);
}